// Round 1
// baseline (3397.458 us; speedup 1.0000x reference)
//
#include <hip/hip_runtime.h>
#include <hip/hip_bf16.h>

#define BB 32
#define SS 512
#define EE 512
#define HH 8
#define DD 64
#define NROW (BB*SS)   // 16384

__device__ __forceinline__ float waveMax(float v){
  #pragma unroll
  for (int o = 32; o > 0; o >>= 1) v = fmaxf(v, __shfl_xor(v, o));
  return v;
}
__device__ __forceinline__ float waveSum(float v){
  #pragma unroll
  for (int o = 32; o > 0; o >>= 1) v += __shfl_xor(v, o);
  return v;
}

// ---------------- K0: tiny precompute: T4 = type_table @ W1, colsums of W2/W3 --------
__global__ __launch_bounds__(512) void k0_pre(const float* __restrict__ type_table,
                       const float* __restrict__ W_int,
                       float* __restrict__ T4, float* __restrict__ cs2, float* __restrict__ cs3)
{
  int e = threadIdx.x;
  int blk = blockIdx.x;
  float a = 0.f;
  if (blk < 4) {
    #pragma unroll 4
    for (int k = 0; k < EE; ++k)
      a += type_table[blk*EE + k] * W_int[(size_t)(EE + k)*EE + e];
    T4[blk*EE + e] = a;
  } else if (blk == 4) {
    #pragma unroll 4
    for (int k = 0; k < EE; ++k) a += W_int[(size_t)(2*EE + k)*EE + e];
    cs2[e] = a;
  } else {
    #pragma unroll 4
    for (int k = 0; k < EE; ++k) a += W_int[(size_t)(3*EE + k)*EE + e];
    cs3[e] = a;
  }
}

// ---------------- K1: inputs = relu(item_emb@W0 + T4[type] + qresp*cs2 + label*cs3 + b) ----
__global__ __launch_bounds__(512) void k1_inputs(
  const int* __restrict__ item_inputs, const int* __restrict__ type_inputs,
  const float* __restrict__ qresp, const float* __restrict__ label,
  const float* __restrict__ use_table, const float* __restrict__ W_int,
  const float* __restrict__ b_int, const float* __restrict__ T4,
  const float* __restrict__ cs2, const float* __restrict__ cs3,
  float* __restrict__ outp)
{
  __shared__ float xs[16][EE];
  int tid = threadIdx.x;
  int row0 = blockIdx.x * 16;
  for (int j = 0; j < 16; ++j) {
    int row = row0 + j;
    int s = row & (SS-1);
    int item = item_inputs[row];
    xs[j][tid] = (s == 0) ? 0.f : use_table[(size_t)item*EE + tid];
  }
  __syncthreads();
  float acc[16];
  #pragma unroll
  for (int j=0;j<16;++j) acc[j]=0.f;
  #pragma unroll 4
  for (int k = 0; k < EE; ++k) {
    float wv = W_int[(size_t)k*EE + tid];
    #pragma unroll
    for (int j=0;j<16;++j) acc[j] += xs[j][k]*wv;
  }
  float bi = b_int[tid], c2 = cs2[tid], c3 = cs3[tid];
  for (int j=0;j<16;++j){
    int row = row0 + j;
    int t = type_inputs[row];
    float v = acc[j] + bi + T4[t*EE + tid] + qresp[row]*c2 + label[row]*c3;
    outp[(size_t)row*EE + tid] = fmaxf(v, 0.f);
  }
}

// ---------------- K2: query_embed gather ----------------
__global__ __launch_bounds__(512) void k2_gather(const int* __restrict__ ids,
  const float* __restrict__ use_table, float* __restrict__ outp)
{
  int tid = threadIdx.x;
  int row0 = blockIdx.x * 8;
  for (int j=0;j<8;++j){
    int row = row0+j;
    outp[(size_t)row*EE + tid] = use_table[(size_t)ids[row]*EE + tid];
  }
}

// ---------------- K3: M = (1-l1)*l2*softmax(tsc) + l1*softmax(rsc) ----------------
__global__ __launch_bounds__(256) void k3_M(
  const float* __restrict__ rel, const float* __restrict__ ts,
  const float* __restrict__ l1p, const float* __restrict__ l2p,
  float* __restrict__ Mout)
{
  int w = threadIdx.x >> 6, lane = threadIdx.x & 63;
  int row = blockIdx.x*4 + w;
  int q = row & (SS-1);
  const float* tr = ts + (size_t)row*SS;
  const float* rr = rel + (size_t)row*SS;
  float tv[8], rv[8];
  float m1 = -INFINITY, m2 = -1e10f;
  #pragma unroll
  for (int j=0;j<8;++j){
    int k = lane + 64*j;
    float t = tr[k];
    tv[j] = (k <= q) ? __expf(-fabsf(t)) : -INFINITY;
    m1 = fmaxf(m1, tv[j]);
    float rvv = (k > q) ? rr[k] : 0.f;
    rv[j] = (rvv == 0.f) ? -10000.f : rvv;   // exact replication of (relm==0) -> -1e4
    m2 = fmaxf(m2, rv[j]);
  }
  m1 = waveMax(m1); m2 = waveMax(m2);
  float s1=0.f, s2=0.f;
  float p1[8], p2[8];
  #pragma unroll
  for (int j=0;j<8;++j){
    p1[j] = __expf(tv[j]-m1); s1 += p1[j];
    p2[j] = __expf(rv[j]-m2); s2 += p2[j];
  }
  s1 = waveSum(s1); s2 = waveSum(s2);
  float l1v = l1p[0], l2v = l2p[0];
  float i1 = (1.f-l1v)*l2v/s1, i2 = l1v/s2;
  float* Mr = Mout + (size_t)row*SS;
  #pragma unroll
  for (int j=0;j<8;++j){
    Mr[lane+64*j] = p1[j]*i1 + p2[j]*i2;
  }
}

// ---------------- K4: projection GEMM: out[b,h,s,d] = X[row]@W + bias ----------------
__global__ __launch_bounds__(512) void k4_proj(
  const float* __restrict__ X, const float* __restrict__ W,
  const float* __restrict__ bias, float* __restrict__ outp)
{
  __shared__ float xs[16][EE];
  int tid = threadIdx.x;
  int row0 = blockIdx.x * 16;
  for (int j=0;j<16;++j) xs[j][tid] = X[(size_t)(row0+j)*EE + tid];
  __syncthreads();
  float acc[16];
  #pragma unroll
  for (int j=0;j<16;++j) acc[j]=0.f;
  #pragma unroll 4
  for (int k=0;k<EE;++k){
    float wv = W[(size_t)k*EE + tid];
    #pragma unroll
    for (int j=0;j<16;++j) acc[j] += xs[j][k]*wv;
  }
  float bv = bias[tid];
  int h = tid >> 6, d = tid & 63;
  #pragma unroll
  for (int j=0;j<16;++j){
    int row = row0+j; int b = row >> 9; int s = row & (SS-1);
    outp[(((size_t)(b*HH + h))*SS + s)*DD + d] = acc[j] + bv;
  }
}

// ---------------- K5: fused attention: out = c1*softmax(QK^T/8)@V + M@V -------------
__global__ __launch_bounds__(256) void k5_attn(
  const float* __restrict__ qbuf, const float* __restrict__ kbuf,
  const float* __restrict__ vbuf, const float* __restrict__ Mbuf,
  const float* __restrict__ l1p, const float* __restrict__ l2p,
  float* __restrict__ outp)
{
  __shared__ float qs[32][68];
  __shared__ float ms[32][68];
  __shared__ float ps[32][68];
  __shared__ float ks[64][65];
  __shared__ float vs[64][65];
  int bh = blockIdx.x; int b = bh >> 3; int h = bh & 7;
  int q0 = blockIdx.y * 32;
  int tid = threadIdx.x; int lane = tid & 63; int w = tid >> 6;
  float c1;
  { float a = l1p[0], c = l2p[0]; c1 = (1.f-a)*(1.f-c); }
  for (int idx = tid; idx < 32*64; idx += 256) {
    int r = idx >> 6, d = idx & 63;
    qs[r][d] = qbuf[((size_t)bh * SS + (q0+r)) * DD + d];
  }
  const int qrb = w * 8;
  float mx[8], li[8], acc[8], macc[8];
  #pragma unroll
  for (int r=0;r<8;++r){ mx[r]=-INFINITY; li[r]=0.f; acc[r]=0.f; macc[r]=0.f; }
  const float scale = 0.125f;

  for (int kt = 0; kt < SS/64; ++kt) {
    __syncthreads();
    for (int idx = tid; idx < 64*64; idx += 256) {
      int r = idx >> 6, d = idx & 63;
      ks[r][d] = kbuf[((size_t)bh * SS + (kt*64+r)) * DD + d];
      vs[r][d] = vbuf[((size_t)bh * SS + (kt*64+r)) * DD + d];
    }
    for (int idx = tid; idx < 32*64; idx += 256) {
      int r = idx >> 6, d = idx & 63;
      ms[r][d] = Mbuf[((size_t)b * SS + (q0+r)) * SS + kt*64 + d];
    }
    __syncthreads();

    bool doscore = (kt*64 <= q0 + qrb + 7);
    if (doscore) {
      float sc[8];
      #pragma unroll
      for (int r=0;r<8;++r) sc[r]=0.f;
      #pragma unroll 4
      for (int g=0; g<16; ++g) {
        float k0 = ks[lane][4*g+0], k1 = ks[lane][4*g+1];
        float k2 = ks[lane][4*g+2], k3 = ks[lane][4*g+3];
        #pragma unroll
        for (int r=0;r<8;++r){
          float4 q4 = *(const float4*)&qs[qrb+r][4*g];
          sc[r] += q4.x*k0 + q4.y*k1 + q4.z*k2 + q4.w*k3;
        }
      }
      int kg = kt*64 + lane;
      #pragma unroll
      for (int r=0;r<8;++r){
        int qg = q0 + qrb + r;
        float s = (kg <= qg) ? sc[r]*scale : -INFINITY;
        float tm = waveMax(s);
        float nm = fmaxf(mx[r], tm);
        float corr = __expf(mx[r]-nm);
        float p = __expf(s - nm);
        float tsum = waveSum(p);
        li[r] = li[r]*corr + tsum;
        mx[r] = nm;
        acc[r] *= corr;
        ps[qrb+r][lane] = p;
      }
      // PV + MV
      #pragma unroll 2
      for (int g=0; g<16; ++g) {
        float v0 = vs[4*g+0][lane], v1 = vs[4*g+1][lane];
        float v2 = vs[4*g+2][lane], v3 = vs[4*g+3][lane];
        #pragma unroll
        for (int r=0;r<8;++r){
          float4 m4 = *(const float4*)&ms[qrb+r][4*g];
          macc[r] += m4.x*v0 + m4.y*v1 + m4.z*v2 + m4.w*v3;
          float4 p4 = *(const float4*)&ps[qrb+r][4*g];
          acc[r] += p4.x*v0 + p4.y*v1 + p4.z*v2 + p4.w*v3;
        }
      }
    } else {
      // MV only
      #pragma unroll 2
      for (int g=0; g<16; ++g) {
        float v0 = vs[4*g+0][lane], v1 = vs[4*g+1][lane];
        float v2 = vs[4*g+2][lane], v3 = vs[4*g+3][lane];
        #pragma unroll
        for (int r=0;r<8;++r){
          float4 m4 = *(const float4*)&ms[qrb+r][4*g];
          macc[r] += m4.x*v0 + m4.y*v1 + m4.z*v2 + m4.w*v3;
        }
      }
    }
  }
  #pragma unroll
  for (int r=0;r<8;++r){
    int qg = q0 + qrb + r;
    float res = c1 * acc[r] / li[r] + macc[r];
    outp[((size_t)b*SS + qg)*EE + h*DD + lane] = res;
  }
}

// ---------------- K6: O += relu(R) ----------------
__global__ void k6_addrelu(float4* __restrict__ O, const float4* __restrict__ R, int n4){
  int i = blockIdx.x*blockDim.x + threadIdx.x;
  int stride = gridDim.x*blockDim.x;
  for (; i < n4; i += stride){
    float4 o = O[i], r = R[i];
    o.x += fmaxf(r.x,0.f); o.y += fmaxf(r.y,0.f);
    o.z += fmaxf(r.z,0.f); o.w += fmaxf(r.w,0.f);
    O[i] = o;
  }
}

// ---------------- K7: h = relu([O, query]@Wf1 + bf1) ----------------
__global__ __launch_bounds__(512) void k7_ffn1(
  const float* __restrict__ O, const float* __restrict__ Q,
  const float* __restrict__ Wf1, const float* __restrict__ bf1,
  float* __restrict__ hbuf)
{
  __shared__ float xs[16][EE];
  int tid = threadIdx.x;
  int row0 = blockIdx.x*16;
  for (int j=0;j<16;++j) xs[j][tid] = O[(size_t)(row0+j)*EE + tid];
  __syncthreads();
  float acc[16];
  #pragma unroll
  for (int j=0;j<16;++j) acc[j]=0.f;
  #pragma unroll 4
  for (int k=0;k<EE;++k){
    float wv = Wf1[(size_t)k*EE + tid];
    #pragma unroll
    for (int j=0;j<16;++j) acc[j] += xs[j][k]*wv;
  }
  __syncthreads();
  for (int j=0;j<16;++j) xs[j][tid] = Q[(size_t)(row0+j)*EE + tid];
  __syncthreads();
  #pragma unroll 4
  for (int k=0;k<EE;++k){
    float wv = Wf1[(size_t)(EE+k)*EE + tid];
    #pragma unroll
    for (int j=0;j<16;++j) acc[j] += xs[j][k]*wv;
  }
  float bv = bf1[tid];
  for (int j=0;j<16;++j)
    hbuf[(size_t)(row0+j)*EE + tid] = fmaxf(acc[j]+bv, 0.f);
}

// ---------------- K8: out = h @ Wf2 + bf2 ----------------
__global__ __launch_bounds__(512) void k8_ffn2(
  const float* __restrict__ hbuf, const float* __restrict__ Wf2,
  const float* __restrict__ bf2, float* __restrict__ outp)
{
  int w = threadIdx.x >> 6, lane = threadIdx.x & 63;
  int row = blockIdx.x*8 + w;
  float s = 0.f;
  #pragma unroll
  for (int j=0;j<8;++j){
    int e = lane + 64*j;
    s += hbuf[(size_t)row*EE + e]*Wf2[e];
  }
  s = waveSum(s);
  if (lane == 0) outp[row] = s + bf2[0];
}

extern "C" void kernel_launch(void* const* d_in, const int* in_sizes, int n_in,
                              void* d_out, int out_size, void* d_ws, size_t ws_size,
                              hipStream_t stream)
{
  const int*   item_inputs = (const int*)d_in[0];
  const float* label_in    = (const float*)d_in[1];
  const int*   type_inputs = (const int*)d_in[2];
  const int*   item_ids    = (const int*)d_in[3];
  const float* rel         = (const float*)d_in[4];
  const float* tstamp      = (const float*)d_in[5];
  const float* qresp       = (const float*)d_in[6];
  const float* use_table   = (const float*)d_in[7];
  const float* type_table  = (const float*)d_in[8];
  const float* W_int       = (const float*)d_in[9];
  const float* b_int       = (const float*)d_in[10];
  const float* Wq          = (const float*)d_in[11];
  const float* bq          = (const float*)d_in[12];
  const float* Wk          = (const float*)d_in[13];
  const float* bk          = (const float*)d_in[14];
  const float* Wv          = (const float*)d_in[15];
  const float* bv          = (const float*)d_in[16];
  const float* Wf1         = (const float*)d_in[17];
  const float* bf1         = (const float*)d_in[18];
  const float* Wf2         = (const float*)d_in[19];
  const float* bf2         = (const float*)d_in[20];
  const float* l1p         = (const float*)d_in[21];
  const float* l2p         = (const float*)d_in[22];
  float* out = (float*)d_out;
  (void)in_sizes; (void)n_in; (void)out_size; (void)ws_size;

  float* wsf = (float*)d_ws;
  size_t NE = (size_t)NROW*EE;       // 8388608
  float* inputsB = wsf;              // layer-0 kv input; later residual R
  float* queryB  = wsf + NE;
  float* Mbuf    = wsf + 2*NE;       // B*S*S == NE
  float* qB      = wsf + 3*NE;       // later: h buffer
  float* kB      = wsf + 4*NE;
  float* vB      = wsf + 5*NE;
  float* OB      = wsf + 6*NE;
  float* T4      = wsf + 7*NE;
  float* cs2     = T4 + 4*EE;
  float* cs3     = cs2 + EE;

  k0_pre   <<<6, 512, 0, stream>>>(type_table, W_int, T4, cs2, cs3);
  k2_gather<<<NROW/8, 512, 0, stream>>>(item_ids, use_table, queryB);
  k1_inputs<<<NROW/16, 512, 0, stream>>>(item_inputs, type_inputs, qresp, label_in,
                                         use_table, W_int, b_int, T4, cs2, cs3, inputsB);
  k3_M     <<<NROW/4, 256, 0, stream>>>(rel, tstamp, l1p, l2p, Mbuf);

  // layer 0
  k4_proj<<<NROW/16, 512, 0, stream>>>(queryB,  Wq,          bq,       qB);
  k4_proj<<<NROW/16, 512, 0, stream>>>(inputsB, Wk,          bk,       kB);
  k4_proj<<<NROW/16, 512, 0, stream>>>(inputsB, Wv,          bv,       vB);
  k5_attn<<<dim3(BB*HH, SS/32), 256, 0, stream>>>(qB, kB, vB, Mbuf, l1p, l2p, OB);

  // layer 1
  k4_proj<<<NROW/16, 512, 0, stream>>>(queryB,  Wq + EE*EE,  bq + EE,  qB);
  k4_proj<<<NROW/16, 512, 0, stream>>>(OB,      Wk + EE*EE,  bk + EE,  kB);
  k4_proj<<<NROW/16, 512, 0, stream>>>(OB,      Wv + EE*EE,  bv + EE,  vB);
  k5_attn<<<dim3(BB*HH, SS/32), 256, 0, stream>>>(qB, kB, vB, Mbuf, l1p, l2p, inputsB);
  k6_addrelu<<<2048, 256, 0, stream>>>((float4*)OB, (const float4*)inputsB, (int)(NE/4));

  // final MLP
  k7_ffn1<<<NROW/16, 512, 0, stream>>>(OB, queryB, Wf1, bf1, qB);
  k8_ffn2<<<NROW/8, 512, 0, stream>>>(qB, Wf2, bf2, out);
}

// Round 2
// 660.683 us; speedup vs baseline: 5.1423x; 5.1423x over previous
//
#include <hip/hip_runtime.h>
#include <hip/hip_bf16.h>

#define BB 32
#define SS 512
#define EE 512
#define HH 8
#define DD 64
#define NROW (BB*SS)   // 16384

typedef unsigned short ushort;
typedef unsigned int u32;
typedef short bf16x8 __attribute__((ext_vector_type(8)));
typedef ushort u16x8 __attribute__((ext_vector_type(8)));
typedef float f32x4 __attribute__((ext_vector_type(4)));

__device__ __forceinline__ float bfu2f(ushort u){ return __uint_as_float(((u32)u)<<16); }
__device__ __forceinline__ ushort f2bfu(float f){
  __hip_bfloat16 h = __float2bfloat16(f);
  return *reinterpret_cast<ushort*>(&h);
}
__device__ __forceinline__ float waveMax(float v){
  #pragma unroll
  for (int o = 32; o > 0; o >>= 1) v = fmaxf(v, __shfl_xor(v, o));
  return v;
}
__device__ __forceinline__ float waveSum(float v){
  #pragma unroll
  for (int o = 32; o > 0; o >>= 1) v += __shfl_xor(v, o);
  return v;
}
__device__ __forceinline__ void async_cp16(const ushort* g, ushort* l){
  __builtin_amdgcn_global_load_lds(
      (const __attribute__((address_space(1))) u32*)g,
      (__attribute__((address_space(3))) u32*)l, 16, 0, 0);
}

// ---------------- transpose fp32 [K][N] -> bf16 [N][K] ----------------
__global__ __launch_bounds__(256) void transpose_bf16(
    const float* __restrict__ in, ushort* __restrict__ out, int K, int N)
{
  __shared__ float tile[32][33];
  int lx = threadIdx.x & 31, ly = threadIdx.x >> 5;  // 32 x 8
  int n = blockIdx.x*32 + lx;
  #pragma unroll
  for (int r=0;r<32;r+=8){
    int k = blockIdx.y*32 + ly + r;
    tile[ly+r][lx] = in[(size_t)k*N + n];
  }
  __syncthreads();
  int kk = blockIdx.y*32 + lx;
  #pragma unroll
  for (int r=0;r<32;r+=8){
    int nn = blockIdx.x*32 + ly + r;
    out[(size_t)nn*K + kk] = f2bfu(tile[lx][ly+r]);
  }
}

// ---------------- K0: T4 = type_table @ W1, colsums of W2/W3 (fp32) ----------------
__global__ __launch_bounds__(512) void k0_pre(const float* __restrict__ type_table,
                       const float* __restrict__ W_int,
                       float* __restrict__ T4, float* __restrict__ cs2, float* __restrict__ cs3)
{
  int e = threadIdx.x;
  int blk = blockIdx.x;
  float a = 0.f;
  if (blk < 4) {
    #pragma unroll 4
    for (int k = 0; k < EE; ++k)
      a += type_table[blk*EE + k] * W_int[(size_t)(EE + k)*EE + e];
    T4[blk*EE + e] = a;
  } else if (blk == 4) {
    #pragma unroll 4
    for (int k = 0; k < EE; ++k) a += W_int[(size_t)(2*EE + k)*EE + e];
    cs2[e] = a;
  } else {
    #pragma unroll 4
    for (int k = 0; k < EE; ++k) a += W_int[(size_t)(3*EE + k)*EE + e];
    cs3[e] = a;
  }
}

// ---------------- gathers: item emb (bf16), query emb (bf16, 2 copies) ----------------
__global__ __launch_bounds__(256) void k_gather(
    const int* __restrict__ item, const int* __restrict__ ids,
    const float* __restrict__ ut,
    ushort* __restrict__ xemb, ushort* __restrict__ qB, ushort* __restrict__ obcat)
{
  int idx = blockIdx.x*256 + threadIdx.x;   // NROW*64 total
  int row = idx >> 6, c = (idx & 63)*8;
  int s = row & (SS-1);
  const float* isrc = ut + (size_t)item[row]*EE + c;
  const float* qsrc = ut + (size_t)ids[row]*EE + c;
  u16x8 xv, qv;
  #pragma unroll
  for (int i=0;i<8;++i){
    xv[i] = (s==0) ? (ushort)0 : f2bfu(isrc[i]);
    qv[i] = f2bfu(qsrc[i]);
  }
  *(u16x8*)(xemb + (size_t)row*EE + c) = xv;
  *(u16x8*)(qB   + (size_t)row*EE + c) = qv;
  *(u16x8*)(obcat+ (size_t)row*1024 + 512 + c) = qv;
}

// ---------------- K3: M = (1-l1)*l2*softmax(tsc) + l1*softmax(rsc) -> bf16 ----------------
__global__ __launch_bounds__(256) void k3_M(
  const float* __restrict__ rel, const float* __restrict__ ts,
  const float* __restrict__ l1p, const float* __restrict__ l2p,
  ushort* __restrict__ Mout)
{
  int w = threadIdx.x >> 6, lane = threadIdx.x & 63;
  int row = blockIdx.x*4 + w;
  int q = row & (SS-1);
  const float* tr = ts + (size_t)row*SS;
  const float* rr = rel + (size_t)row*SS;
  float tv[8], rv[8];
  float m1 = -INFINITY, m2 = -1e10f;
  #pragma unroll
  for (int j=0;j<8;++j){
    int k = lane + 64*j;
    float t = tr[k];
    tv[j] = (k <= q) ? __expf(-fabsf(t)) : -INFINITY;
    m1 = fmaxf(m1, tv[j]);
    float rvv = (k > q) ? rr[k] : 0.f;
    rv[j] = (rvv == 0.f) ? -10000.f : rvv;
    m2 = fmaxf(m2, rv[j]);
  }
  m1 = waveMax(m1); m2 = waveMax(m2);
  float s1=0.f, s2=0.f;
  float p1[8], p2[8];
  #pragma unroll
  for (int j=0;j<8;++j){
    p1[j] = __expf(tv[j]-m1); s1 += p1[j];
    p2[j] = __expf(rv[j]-m2); s2 += p2[j];
  }
  s1 = waveSum(s1); s2 = waveSum(s2);
  float l1v = l1p[0], l2v = l2p[0];
  float i1 = (1.f-l1v)*l2v/s1, i2 = l1v/s2;
  ushort* Mr = Mout + (size_t)row*SS;
  #pragma unroll
  for (int j=0;j<8;++j)
    Mr[lane+64*j] = f2bfu(p1[j]*i1 + p2[j]*i2);
}

// ---------------- MFMA GEMM: C = A[M][K](lda) @ Bt[N][K]^T, bf16 in/out ----------------
// MODE 0: C[row*ldc+col]; MODE 1: [b,h,s,d]; MODE 2: Vt[b][e][s]
// FLAGS: 1=bias, 2=relu, 4=add-to-C, 8=k1 epilogue
template<int MODE, int FLAGS>
__global__ __launch_bounds__(256) void gemm_bt(
    const ushort* __restrict__ A, int lda, size_t sA,
    const ushort* __restrict__ Bt, size_t sB,
    ushort* __restrict__ C, int ldc, size_t sC,
    const float* __restrict__ bias, int K,
    const int* __restrict__ typeIdx, const float* __restrict__ T4f,
    const float* __restrict__ cs2, const float* __restrict__ cs3,
    const float* __restrict__ qresp, const float* __restrict__ label)
{
  __shared__ ushort As[128*32];
  __shared__ ushort Bs[128*32];
  int t = threadIdx.x;
  int w = t >> 6, l = t & 63;
  int row0 = blockIdx.x * 128;
  int n0 = blockIdx.y * 128;
  int z = blockIdx.z;
  const ushort* Ab = A + (size_t)z*sA;
  const ushort* Bb = Bt + (size_t)z*sB;
  ushort* Cb = C + (size_t)z*sC;

  f32x4 acc[4][4];
  f32x4 zero4 = {0.f,0.f,0.f,0.f};
  #pragma unroll
  for (int i=0;i<4;++i)
    #pragma unroll
    for (int j=0;j<4;++j) acc[i][j] = zero4;

  int wr = w >> 1, wc = w & 1;
  int lr = l & 15, lg = l >> 4;
  int arow = wr*64 + lr;
  int brow = wc*64 + lr;
  int kgrp = lg*8;

  for (int k0 = 0; k0 < K; k0 += 32) {
    #pragma unroll
    for (int j=0;j<2;++j){
      int off = (j*256 + t)*8;           // ushort offset within 128x32 tile
      int r = off >> 5, kc = off & 31;
      async_cp16(Ab + (size_t)(row0 + r)*lda + k0 + kc, As + off);
      async_cp16(Bb + (size_t)(n0  + r)*K   + k0 + kc, Bs + off);
    }
    asm volatile("s_waitcnt vmcnt(0)" ::: "memory");
    __syncthreads();
    bf16x8 af[4], bfr[4];
    #pragma unroll
    for (int i=0;i<4;++i){
      af[i]  = *(const bf16x8*)(As + (arow + i*16)*32 + kgrp);
      bfr[i] = *(const bf16x8*)(Bs + (brow + i*16)*32 + kgrp);
    }
    #pragma unroll
    for (int i=0;i<4;++i)
      #pragma unroll
      for (int j=0;j<4;++j)
        acc[i][j] = __builtin_amdgcn_mfma_f32_16x16x32_bf16(af[i], bfr[j], acc[i][j], 0,0,0);
    __syncthreads();
  }

  int crow0 = row0 + wr*64 + lg*4;
  int ccol0 = n0 + wc*64 + lr;
  #pragma unroll
  for (int mi=0;mi<4;++mi){
    #pragma unroll
    for (int ni=0;ni<4;++ni){
      int col = ccol0 + ni*16;
      float bv = 0.f;
      if constexpr ((FLAGS & 1) != 0) bv = bias[col];
      #pragma unroll
      for (int j=0;j<4;++j){
        int row = crow0 + mi*16 + j;
        float v = acc[mi][ni][j] + bv;
        if constexpr ((FLAGS & 8) != 0) {
          int tt = typeIdx[row];
          v += T4f[tt*EE + col] + qresp[row]*cs2[col] + label[row]*cs3[col];
        }
        if constexpr ((FLAGS & 2) != 0) v = fmaxf(v, 0.f);
        size_t idx;
        if constexpr (MODE == 0)      idx = (size_t)row*ldc + col;
        else if constexpr (MODE == 1) idx = ((size_t)(row>>9)*HH + (col>>6))*(SS*DD) + (size_t)(row&(SS-1))*DD + (col&63);
        else                          idx = (size_t)(row>>9)*(EE*SS) + (size_t)col*SS + (row&(SS-1));
        if constexpr ((FLAGS & 4) != 0) v += bfu2f(Cb[idx]);
        Cb[idx] = f2bfu(v);
      }
    }
  }
}

// ---------------- flash attention: out = c1 * softmax(QK^T/8) @ V (causal) ----------------
// qb,kb: [b,h,s,d] bf16 ; vt: [b][e][s] bf16 ; out: bf16 row-major with stride ldo
__global__ __launch_bounds__(256) void flash_attn(
    const ushort* __restrict__ qb, const ushort* __restrict__ kb,
    const ushort* __restrict__ vt,
    const float* __restrict__ l1p, const float* __restrict__ l2p,
    ushort* __restrict__ outp, int ldo)
{
  __shared__ ushort ps[4][16][72];
  int bh = blockIdx.x;
  int b = bh >> 3, h = bh & 7;
  int q0 = blockIdx.y * 64;
  int t = threadIdx.x, w = t >> 6, l = t & 63;
  int lr = l & 15, lg = l >> 4;
  int qw = q0 + w*16;
  float c1 = (1.f - l1p[0]) * (1.f - l2p[0]);

  const ushort* qrow = qb + ((size_t)bh*SS + qw + lr)*DD;
  bf16x8 qa[2];
  qa[0] = *(const bf16x8*)(qrow + lg*8);
  qa[1] = *(const bf16x8*)(qrow + 32 + lg*8);

  f32x4 acc[4];
  f32x4 zero4 = {0.f,0.f,0.f,0.f};
  #pragma unroll
  for (int i=0;i<4;++i) acc[i] = zero4;
  float m[4], li[4];
  #pragma unroll
  for (int j=0;j<4;++j){ m[j] = -1e30f; li[j] = 0.f; }

  const ushort* kbase0 = kb + (size_t)bh*SS*DD;
  const ushort* vbase  = vt + ((size_t)b*EE + h*64)*SS;
  int ktmax = (qw + 15) >> 6;

  for (int kt = 0; kt <= ktmax; ++kt) {
    int kv0 = kt*64;
    // scores: A=Q[q][d], B=K^T[d][kv]
    f32x4 sc[4];
    #pragma unroll
    for (int i=0;i<4;++i) sc[i] = zero4;
    const ushort* kbase = kbase0 + (size_t)kv0*DD;
    #pragma unroll
    for (int dh=0; dh<2; ++dh){
      #pragma unroll
      for (int ni=0; ni<4; ++ni){
        bf16x8 kf = *(const bf16x8*)(kbase + (size_t)(ni*16 + lr)*DD + dh*32 + lg*8);
        sc[ni] = __builtin_amdgcn_mfma_f32_16x16x32_bf16(qa[dh], kf, sc[ni], 0,0,0);
      }
    }
    // mask + scale
    float sv[4][4];
    #pragma unroll
    for (int ni=0;ni<4;++ni){
      int kv = kv0 + ni*16 + lr;
      #pragma unroll
      for (int j=0;j<4;++j){
        int q = qw + lg*4 + j;
        sv[ni][j] = (kv <= q) ? sc[ni][j]*0.125f : -1e30f;
      }
    }
    // online softmax per q-row (row j lives in 16-lane group lg)
    #pragma unroll
    for (int j=0;j<4;++j){
      float rm = fmaxf(fmaxf(sv[0][j],sv[1][j]), fmaxf(sv[2][j],sv[3][j]));
      rm = fmaxf(rm, __shfl_xor(rm,1));
      rm = fmaxf(rm, __shfl_xor(rm,2));
      rm = fmaxf(rm, __shfl_xor(rm,4));
      rm = fmaxf(rm, __shfl_xor(rm,8));
      float nm = fmaxf(m[j], rm);
      float corr = __expf(m[j]-nm);
      m[j] = nm;
      float rs = 0.f;
      #pragma unroll
      for (int ni=0;ni<4;++ni){
        float pp = __expf(sv[ni][j]-nm);
        rs += pp;
        ps[w][lg*4+j][ni*16+lr] = f2bfu(pp);
      }
      rs += __shfl_xor(rs,1);
      rs += __shfl_xor(rs,2);
      rs += __shfl_xor(rs,4);
      rs += __shfl_xor(rs,8);
      li[j] = li[j]*corr + rs;
      #pragma unroll
      for (int ni=0;ni<4;++ni) acc[ni][j] *= corr;
    }
    // PV: A=P[q][kv] from LDS, B=V[kv][d] from Vt
    #pragma unroll
    for (int kh=0; kh<2; ++kh){
      bf16x8 pa = *(const bf16x8*)(&ps[w][lr][kh*32 + lg*8]);
      #pragma unroll
      for (int ni=0; ni<4; ++ni){
        bf16x8 vf = *(const bf16x8*)(vbase + (size_t)(ni*16 + lr)*SS + kv0 + kh*32 + lg*8);
        acc[ni] = __builtin_amdgcn_mfma_f32_16x16x32_bf16(pa, vf, acc[ni], 0,0,0);
      }
    }
  }
  #pragma unroll
  for (int ni=0;ni<4;++ni){
    int d = ni*16 + lr;
    #pragma unroll
    for (int j=0;j<4;++j){
      int q = qw + lg*4 + j;
      float v = c1 * acc[ni][j] / li[j];
      outp[(size_t)(b*SS + q)*ldo + h*64 + d] = f2bfu(v);
    }
  }
}

// ---------------- O[:, :512] += relu(R) ----------------
__global__ __launch_bounds__(256) void k6_addrelu(ushort* __restrict__ O, const ushort* __restrict__ R){
  int idx = blockIdx.x*256 + threadIdx.x;
  int row = idx >> 6, c = (idx & 63)*8;
  ushort* op = O + (size_t)row*1024 + c;
  const ushort* rp = R + (size_t)row*EE + c;
  u16x8 ov = *(const u16x8*)op;
  u16x8 rv = *(const u16x8*)rp;
  u16x8 res;
  #pragma unroll
  for (int i=0;i<8;++i) res[i] = f2bfu(bfu2f(ov[i]) + fmaxf(bfu2f(rv[i]), 0.f));
  *(u16x8*)op = res;
}

// ---------------- out = h @ Wf2 + bf2 ----------------
__global__ __launch_bounds__(256) void k_ffn2(
    const ushort* __restrict__ hB, const float* __restrict__ Wf2,
    const float* __restrict__ bf2p, float* __restrict__ outp)
{
  int w = threadIdx.x >> 6, l = threadIdx.x & 63;
  int row = blockIdx.x*4 + w;
  bf16x8 hv = *(const bf16x8*)(hB + (size_t)row*EE + l*8);
  float s = 0.f;
  #pragma unroll
  for (int i=0;i<8;++i) s += bfu2f((ushort)hv[i]) * Wf2[l*8+i];
  s = waveSum(s);
  if (l == 0) outp[row] = s + bf2p[0];
}

extern "C" void kernel_launch(void* const* d_in, const int* in_sizes, int n_in,
                              void* d_out, int out_size, void* d_ws, size_t ws_size,
                              hipStream_t stream)
{
  const int*   item_inputs = (const int*)d_in[0];
  const float* label_in    = (const float*)d_in[1];
  const int*   type_inputs = (const int*)d_in[2];
  const int*   item_ids    = (const int*)d_in[3];
  const float* rel         = (const float*)d_in[4];
  const float* tstamp      = (const float*)d_in[5];
  const float* qresp       = (const float*)d_in[6];
  const float* use_table   = (const float*)d_in[7];
  const float* type_table  = (const float*)d_in[8];
  const float* W_int       = (const float*)d_in[9];
  const float* b_int       = (const float*)d_in[10];
  const float* Wq          = (const float*)d_in[11];
  const float* bq          = (const float*)d_in[12];
  const float* Wk          = (const float*)d_in[13];
  const float* bk          = (const float*)d_in[14];
  const float* Wv          = (const float*)d_in[15];
  const float* bv          = (const float*)d_in[16];
  const float* Wf1         = (const float*)d_in[17];
  const float* bf1         = (const float*)d_in[18];
  const float* Wf2         = (const float*)d_in[19];
  const float* bf2         = (const float*)d_in[20];
  const float* l1p         = (const float*)d_in[21];
  const float* l2p         = (const float*)d_in[22];
  float* out = (float*)d_out;
  (void)in_sizes; (void)n_in; (void)out_size; (void)ws_size;

  char* p = (char*)d_ws;
  auto alloc = [&](size_t bytes)->char*{ char* r = p; p += (bytes + 255) & ~(size_t)255; return r; };
  const size_t NE2 = (size_t)NROW*EE*2;   // bf16 bytes of a [16384][512] buffer
  ushort* xemb    = (ushort*)alloc(NE2);
  ushort* queryB  = (ushort*)alloc(NE2);
  ushort* inputsB = (ushort*)alloc(NE2);
  ushort* Mbuf    = (ushort*)alloc((size_t)BB*SS*SS*2);
  ushort* qB      = (ushort*)alloc(NE2);
  ushort* kB      = (ushort*)alloc(NE2);
  ushort* VtB     = (ushort*)alloc(NE2);
  ushort* OBcat   = (ushort*)alloc((size_t)NROW*1024*2);
  ushort* RB      = (ushort*)alloc(NE2);
  ushort* hB      = (ushort*)alloc(NE2);
  ushort* WtI     = (ushort*)alloc((size_t)EE*EE*2);
  ushort* WtQ0    = (ushort*)alloc((size_t)EE*EE*2);
  ushort* WtQ1    = (ushort*)alloc((size_t)EE*EE*2);
  ushort* WtK0    = (ushort*)alloc((size_t)EE*EE*2);
  ushort* WtK1    = (ushort*)alloc((size_t)EE*EE*2);
  ushort* WtV0    = (ushort*)alloc((size_t)EE*EE*2);
  ushort* WtV1    = (ushort*)alloc((size_t)EE*EE*2);
  ushort* WtF1    = (ushort*)alloc((size_t)EE*1024*2);
  float*  T4f     = (float*)alloc(4*EE*4);
  float*  cs2     = (float*)alloc(EE*4);
  float*  cs3     = (float*)alloc(EE*4);

  const int nullsI = 0; (void)nullsI;
  const int* nullI = nullptr;
  const float* nullF = nullptr;

  // weight prep
  transpose_bf16<<<dim3(16,16),256,0,stream>>>(W_int,          WtI,  512, 512);
  transpose_bf16<<<dim3(16,16),256,0,stream>>>(Wq,             WtQ0, 512, 512);
  transpose_bf16<<<dim3(16,16),256,0,stream>>>(Wq + 262144,    WtQ1, 512, 512);
  transpose_bf16<<<dim3(16,16),256,0,stream>>>(Wk,             WtK0, 512, 512);
  transpose_bf16<<<dim3(16,16),256,0,stream>>>(Wk + 262144,    WtK1, 512, 512);
  transpose_bf16<<<dim3(16,16),256,0,stream>>>(Wv,             WtV0, 512, 512);
  transpose_bf16<<<dim3(16,16),256,0,stream>>>(Wv + 262144,    WtV1, 512, 512);
  transpose_bf16<<<dim3(16,32),256,0,stream>>>(Wf1,            WtF1, 1024, 512);
  k0_pre<<<6,512,0,stream>>>(type_table, W_int, T4f, cs2, cs3);
  k_gather<<<NROW/4,256,0,stream>>>(item_inputs, item_ids, use_table, xemb, queryB, OBcat);
  k3_M<<<NROW/4,256,0,stream>>>(rel, tstamp, l1p, l2p, Mbuf);

  // inputs = relu(item@W0 + T4[type] + qresp*cs2 + label*cs3 + b_int)
  gemm_bt<0,11><<<dim3(128,4,1),256,0,stream>>>(xemb,512,0, WtI,0, inputsB,512,0, b_int, 512,
                                                type_inputs, T4f, cs2, cs3, qresp, label_in);
  // layer 0
  gemm_bt<1,1><<<dim3(128,4,1),256,0,stream>>>(queryB,512,0,  WtQ0,0, qB,0,0, bq, 512, nullI,nullF,nullF,nullF,nullF,nullF);
  gemm_bt<1,1><<<dim3(128,4,1),256,0,stream>>>(inputsB,512,0, WtK0,0, kB,0,0, bk, 512, nullI,nullF,nullF,nullF,nullF,nullF);
  gemm_bt<2,1><<<dim3(128,4,1),256,0,stream>>>(inputsB,512,0, WtV0,0, VtB,0,0, bv, 512, nullI,nullF,nullF,nullF,nullF,nullF);
  flash_attn<<<dim3(BB*HH, SS/64),256,0,stream>>>(qB, kB, VtB, l1p, l2p, OBcat, 1024);
  gemm_bt<0,4><<<dim3(4,4,32),256,0,stream>>>(Mbuf,512,(size_t)SS*SS, VtB,(size_t)EE*SS,
                                              OBcat,1024,(size_t)SS*1024, nullF, 512,
                                              nullI,nullF,nullF,nullF,nullF,nullF);
  // layer 1
  gemm_bt<1,1><<<dim3(128,4,1),256,0,stream>>>(queryB,512,0, WtQ1,0, qB,0,0, bq+EE, 512, nullI,nullF,nullF,nullF,nullF,nullF);
  gemm_bt<1,1><<<dim3(128,4,1),256,0,stream>>>(OBcat,1024,0, WtK1,0, kB,0,0, bk+EE, 512, nullI,nullF,nullF,nullF,nullF,nullF);
  gemm_bt<2,1><<<dim3(128,4,1),256,0,stream>>>(OBcat,1024,0, WtV1,0, VtB,0,0, bv+EE, 512, nullI,nullF,nullF,nullF,nullF,nullF);
  flash_attn<<<dim3(BB*HH, SS/64),256,0,stream>>>(qB, kB, VtB, l1p, l2p, RB, 512);
  gemm_bt<0,4><<<dim3(4,4,32),256,0,stream>>>(Mbuf,512,(size_t)SS*SS, VtB,(size_t)EE*SS,
                                              RB,512,(size_t)SS*EE, nullF, 512,
                                              nullI,nullF,nullF,nullF,nullF,nullF);
  k6_addrelu<<<NROW/4,256,0,stream>>>(OBcat, RB);
  // final MLP
  gemm_bt<0,3><<<dim3(128,4,1),256,0,stream>>>(OBcat,1024,0, WtF1,0, hB,512,0, bf1, 1024,
                                               nullI,nullF,nullF,nullF,nullF,nullF);
  k_ffn2<<<NROW/4,256,0,stream>>>(hB, Wf2, bf2, out);
}